// Round 9
// baseline (176.303 us; speedup 1.0000x reference)
//
#include <hip/hip_runtime.h>

#define EPS 1e-5f
#define SLOPE 0.2f

typedef float v2f __attribute__((ext_vector_type(2)));

// packed fma: (s,s)*w + a -> v_pk_fma_f32 when available
__device__ __forceinline__ v2f pkfma(float s, v2f w, v2f a) {
  v2f sv = {s, s};
  return __builtin_elementwise_fma(sv, w, a);
}

// Dual-row LayerNorm + LeakyReLU over 2*N2 elements held as N2 packed float2.
template<int N2>
__device__ __forceinline__ void ln_lrelu_pk2(v2f* __restrict__ ha, v2f* __restrict__ hb,
                                             const float* __restrict__ g,
                                             const float* __restrict__ b) {
  const v2f* g2 = reinterpret_cast<const v2f*>(g);
  const v2f* b2 = reinterpret_cast<const v2f*>(b);
  const float invN = 1.0f / (2 * N2);
  float ma, mb, va, vb;
  if constexpr (N2 >= 2) {
    v2f sa0 = {0.f, 0.f}, sa1 = {0.f, 0.f}, sb0 = {0.f, 0.f}, sb1 = {0.f, 0.f};
#pragma unroll
    for (int j = 0; j < N2; j += 2) {
      sa0 += ha[j]; sa1 += ha[j + 1];
      sb0 += hb[j]; sb1 += hb[j + 1];
    }
    v2f sat = sa0 + sa1, sbt = sb0 + sb1;
    ma = (sat.x + sat.y) * invN;
    mb = (sbt.x + sbt.y) * invN;
    v2f qa0 = {0.f, 0.f}, qa1 = {0.f, 0.f}, qb0 = {0.f, 0.f}, qb1 = {0.f, 0.f};
#pragma unroll
    for (int j = 0; j < N2; j += 2) {
      v2f da0 = ha[j] - ma, da1 = ha[j + 1] - ma;
      v2f db0 = hb[j] - mb, db1 = hb[j + 1] - mb;
      qa0 = __builtin_elementwise_fma(da0, da0, qa0);
      qa1 = __builtin_elementwise_fma(da1, da1, qa1);
      qb0 = __builtin_elementwise_fma(db0, db0, qb0);
      qb1 = __builtin_elementwise_fma(db1, db1, qb1);
    }
    v2f qat = qa0 + qa1, qbt = qb0 + qb1;
    va = (qat.x + qat.y) * invN;
    vb = (qbt.x + qbt.y) * invN;
  } else {
    ma = (ha[0].x + ha[0].y) * 0.5f;
    mb = (hb[0].x + hb[0].y) * 0.5f;
    float dax = ha[0].x - ma, day = ha[0].y - ma;
    float dbx = hb[0].x - mb, dby = hb[0].y - mb;
    va = (dax * dax + day * day) * 0.5f;
    vb = (dbx * dbx + dby * dby) * 0.5f;
  }
  const float rsa = rsqrtf(va + EPS);
  const float rsb = rsqrtf(vb + EPS);
#pragma unroll
  for (int j = 0; j < N2; ++j) {
    v2f gj = g2[j], bj = b2[j];
    v2f ta = (ha[j] - ma) * rsa * gj + bj;
    v2f tb = (hb[j] - mb) * rsb * gj + bj;
    ha[j] = __builtin_elementwise_max(ta, SLOPE * ta);
    hb[j] = __builtin_elementwise_max(tb, SLOPE * tb);
  }
}

// Dual-row Linear: each weight v2f is loaded once (wave-uniform) and feeds
// two independent packed FMA streams.
template<int DIN, int DOUT2>
__device__ __forceinline__ void linear_pk2(const v2f* ha, const v2f* hb,
                                           v2f* oa, v2f* ob,
                                           const float* __restrict__ W) {
#pragma unroll
  for (int j = 0; j < DOUT2; ++j) { oa[j] = (v2f){0.f, 0.f}; ob[j] = (v2f){0.f, 0.f}; }
#pragma unroll
  for (int k = 0; k < DIN; ++k) {
    float xa = (k & 1) ? ha[k >> 1].y : ha[k >> 1].x;
    float xb = (k & 1) ? hb[k >> 1].y : hb[k >> 1].x;
    const v2f* wr = reinterpret_cast<const v2f*>(W + k * (DOUT2 * 2));
#pragma unroll
    for (int j = 0; j < DOUT2; ++j) {
      v2f w = wr[j];
      oa[j] = pkfma(xa, w, oa[j]);
      ob[j] = pkfma(xb, w, ob[j]);
    }
  }
}

__global__ __launch_bounds__(256) void disc_fused(
    const float* __restrict__ x,
    const float* __restrict__ W1, const float* __restrict__ g1, const float* __restrict__ b1,
    const float* __restrict__ W2, const float* __restrict__ g2, const float* __restrict__ b2,
    const float* __restrict__ W3, const float* __restrict__ g3, const float* __restrict__ b3,
    const float* __restrict__ W4, const float* __restrict__ g4, const float* __restrict__ b4,
    const float* __restrict__ W5, const float* __restrict__ g5, const float* __restrict__ b5,
    const float* __restrict__ W6, const float* __restrict__ g6, const float* __restrict__ b6,
    const float* __restrict__ W7, const float* __restrict__ g7, const float* __restrict__ b7,
    const float* __restrict__ W8, const float* __restrict__ b8,
    float* __restrict__ out, int nrows) {
  // Occupancy governor: 45056B LDS -> 3 blocks/CU -> VGPR budget ~170, so the
  // dual-row live set (~140) stays in registers. (R5 evidence: the allocator
  // grants >64 VGPRs without spilling only when LDS caps blocks/CU.)
  __shared__ float ldspad[11264];
  if (threadIdx.x == 0) *(volatile float*)&ldspad[0] = 0.f;

  const int tid = threadIdx.x;
  const long ra = (long)blockIdx.x * 512 + 2 * (long)tid;  // adjacent row pair
  if (ra >= (long)nrows) return;
  long rb = ra + 1;
  const bool bok = rb < (long)nrows;
  if (!bok) rb = ra;

  const float4* __restrict__ xa4 = reinterpret_cast<const float4*>(x) + ra * 32;
  const float4* __restrict__ xb4 = reinterpret_cast<const float4*>(x) + rb * 32;

  // ---- Layer 1 (128->32), both rows against ONE weight walk. Bursts of
  // 8 float4 per row fully consume each 128B line within the burst.
  v2f h1a[16], h1b[16];
#pragma unroll
  for (int j = 0; j < 16; ++j) { h1a[j] = (v2f){0.f, 0.f}; h1b[j] = (v2f){0.f, 0.f}; }

#pragma unroll 1
  for (int cc = 0; cc < 4; ++cc) {   // 4 chunks of 32 columns
    float4 A[8], B[8];
#pragma unroll
    for (int q = 0; q < 8; ++q) A[q] = xa4[cc * 8 + q];
#pragma unroll
    for (int q = 0; q < 8; ++q) B[q] = xb4[cc * 8 + q];
#pragma unroll
    for (int q = 0; q < 8; ++q) {
#pragma unroll
      for (int kk = 0; kk < 4; ++kk) {
        float xka = (kk == 0) ? A[q].x : (kk == 1) ? A[q].y
                  : (kk == 2) ? A[q].z : A[q].w;
        float xkb = (kk == 0) ? B[q].x : (kk == 1) ? B[q].y
                  : (kk == 2) ? B[q].z : B[q].w;
        const v2f* wr =
            reinterpret_cast<const v2f*>(W1 + (cc * 32 + q * 4 + kk) * 32);
#pragma unroll
        for (int j = 0; j < 16; ++j) {
          v2f w = wr[j];
          h1a[j] = pkfma(xka, w, h1a[j]);
          h1b[j] = pkfma(xkb, w, h1b[j]);
        }
      }
    }
  }
  ln_lrelu_pk2<16>(h1a, h1b, g1, b1);

  // ---- Layer 2 (32->64) streamed, dual-row: h2 never register-resident.
  const v2f* W2v = reinterpret_cast<const v2f*>(W2);

  // Pass 1: LN stats via E[x^2]-m^2 (EPS floors the variance -> safe).
  float suma = 0.f, sqa = 0.f, sumb = 0.f, sqb = 0.f;
#pragma unroll 1
  for (int jb = 0; jb < 16; ++jb) {
    v2f a01 = {0.f, 0.f}, a23 = {0.f, 0.f}, c01 = {0.f, 0.f}, c23 = {0.f, 0.f};
#pragma unroll
    for (int k = 0; k < 32; ++k) {
      float xa = (k & 1) ? h1a[k >> 1].y : h1a[k >> 1].x;
      float xb = (k & 1) ? h1b[k >> 1].y : h1b[k >> 1].x;
      v2f w01 = W2v[k * 32 + jb * 2], w23 = W2v[k * 32 + jb * 2 + 1];
      a01 = pkfma(xa, w01, a01); a23 = pkfma(xa, w23, a23);
      c01 = pkfma(xb, w01, c01); c23 = pkfma(xb, w23, c23);
    }
    suma += (a01.x + a01.y) + (a23.x + a23.y);
    sqa = fmaf(a01.x, a01.x, sqa); sqa = fmaf(a01.y, a01.y, sqa);
    sqa = fmaf(a23.x, a23.x, sqa); sqa = fmaf(a23.y, a23.y, sqa);
    sumb += (c01.x + c01.y) + (c23.x + c23.y);
    sqb = fmaf(c01.x, c01.x, sqb); sqb = fmaf(c01.y, c01.y, sqb);
    sqb = fmaf(c23.x, c23.x, sqb); sqb = fmaf(c23.y, c23.y, sqb);
  }
  const float m2a = suma * (1.0f / 64.0f);
  const float v2a = fmaf(-m2a, m2a, sqa * (1.0f / 64.0f));
  const float rs2a = rsqrtf(v2a + EPS);
  const float m2b = sumb * (1.0f / 64.0f);
  const float v2b = fmaf(-m2b, m2b, sqb * (1.0f / 64.0f));
  const float rs2b = rsqrtf(v2b + EPS);

  // Pass 2: recompute h2 block, LN+LeakyReLU, fuse into h3 accumulation.
  v2f h3a[16], h3b[16];
#pragma unroll
  for (int i = 0; i < 16; ++i) { h3a[i] = (v2f){0.f, 0.f}; h3b[i] = (v2f){0.f, 0.f}; }
#pragma unroll 1
  for (int jb = 0; jb < 16; ++jb) {
    v2f a01 = {0.f, 0.f}, a23 = {0.f, 0.f}, c01 = {0.f, 0.f}, c23 = {0.f, 0.f};
#pragma unroll
    for (int k = 0; k < 32; ++k) {
      float xa = (k & 1) ? h1a[k >> 1].y : h1a[k >> 1].x;
      float xb = (k & 1) ? h1b[k >> 1].y : h1b[k >> 1].x;
      v2f w01 = W2v[k * 32 + jb * 2], w23 = W2v[k * 32 + jb * 2 + 1];
      a01 = pkfma(xa, w01, a01); a23 = pkfma(xa, w23, a23);
      c01 = pkfma(xb, w01, c01); c23 = pkfma(xb, w23, c23);
    }
#pragma unroll
    for (int u = 0; u < 4; ++u) {
      float av = (u == 0) ? a01.x : (u == 1) ? a01.y : (u == 2) ? a23.x : a23.y;
      float cv = (u == 0) ? c01.x : (u == 1) ? c01.y : (u == 2) ? c23.x : c23.y;
      int j = jb * 4 + u;
      float gj = g2[j], bj = b2[j];
      float ya = (av - m2a) * rs2a * gj + bj;
      float yb = (cv - m2b) * rs2b * gj + bj;
      ya = fmaxf(ya, SLOPE * ya);
      yb = fmaxf(yb, SLOPE * yb);
      const v2f* wr3 = reinterpret_cast<const v2f*>(W3 + j * 32);
#pragma unroll
      for (int i = 0; i < 16; ++i) {
        v2f w = wr3[i];
        h3a[i] = pkfma(ya, w, h3a[i]);
        h3b[i] = pkfma(yb, w, h3b[i]);
      }
    }
  }
  ln_lrelu_pk2<16>(h3a, h3b, g3, b3);

  v2f h4a[8], h4b[8];
  linear_pk2<32, 8>(h3a, h3b, h4a, h4b, W4); ln_lrelu_pk2<8>(h4a, h4b, g4, b4);
  v2f h5a[4], h5b[4];
  linear_pk2<16, 4>(h4a, h4b, h5a, h5b, W5); ln_lrelu_pk2<4>(h5a, h5b, g5, b5);
  v2f h6a[2], h6b[2];
  linear_pk2<8, 2>(h5a, h5b, h6a, h6b, W6);  ln_lrelu_pk2<2>(h6a, h6b, g6, b6);
  v2f h7a[1], h7b[1];
  linear_pk2<4, 1>(h6a, h6b, h7a, h7b, W7);  ln_lrelu_pk2<1>(h7a, h7b, g7, b7);

  const float w80 = W8[0], w81 = W8[1], bb8 = b8[0];
  out[ra] = fmaf(h7a[0].y, w81, fmaf(h7a[0].x, w80, bb8));
  if (bok) out[rb] = fmaf(h7b[0].y, w81, fmaf(h7b[0].x, w80, bb8));
}

extern "C" void kernel_launch(void* const* d_in, const int* in_sizes, int n_in,
                              void* d_out, int out_size, void* d_ws, size_t ws_size,
                              hipStream_t stream) {
  const float* x  = (const float*)d_in[0];
  const float* W1 = (const float*)d_in[1];
  const float* g1 = (const float*)d_in[2];
  const float* b1 = (const float*)d_in[3];
  const float* W2 = (const float*)d_in[4];
  const float* g2 = (const float*)d_in[5];
  const float* b2 = (const float*)d_in[6];
  const float* W3 = (const float*)d_in[7];
  const float* g3 = (const float*)d_in[8];
  const float* b3 = (const float*)d_in[9];
  const float* W4 = (const float*)d_in[10];
  const float* g4 = (const float*)d_in[11];
  const float* b4 = (const float*)d_in[12];
  const float* W5 = (const float*)d_in[13];
  const float* g5 = (const float*)d_in[14];
  const float* b5 = (const float*)d_in[15];
  const float* W6 = (const float*)d_in[16];
  const float* g6 = (const float*)d_in[17];
  const float* b6 = (const float*)d_in[18];
  const float* W7 = (const float*)d_in[19];
  const float* g7 = (const float*)d_in[20];
  const float* b7 = (const float*)d_in[21];
  const float* W8 = (const float*)d_in[22];
  const float* b8 = (const float*)d_in[23];
  float* out = (float*)d_out;

  const int nrows = in_sizes[0] / 128;            // 524288
  const int grid = (nrows + 511) / 512;           // 1024 blocks x 2 rows/thread
  hipLaunchKernelGGL(disc_fused, dim3(grid), dim3(256), 0, stream,
                     x, W1, g1, b1, W2, g2, b2, W3, g3, b3, W4, g4, b4,
                     W5, g5, b5, W6, g6, b6, W7, g7, b7, W8, b8, out, nrows);
}